// Round 4
// baseline (186.856 us; speedup 1.0000x reference)
//
#include <hip/hip_runtime.h>
#include <math.h>

// ---------------- problem constants ----------------
#define BATCH   16
#define T_LEN   262144
#define NB      16          // biquad stages
#define L       32          // samples per chunk (32 -> 2 waves/SIMD)
#define GRP     64          // chunks per group (== wave width)
#define NG      128         // groups per batch  (T_LEN / (L*GRP))
#define NCHUNK  8192        // chunks per batch  (T_LEN / L)

#define DPI 3.14159265358979323846264338327950288

// ---------------- ws layout (in floats) ----------------
#define OFF_COEF  0                         // [16][96]
#define OFF_AL    1536                      // [16][32][32]  A^32
#define OFF_AG    17920                     // [16][32][32]  A^2048
#define OFF_QEND  34304                     // [16][128][32]
#define OFF_SARR  99840                     // [16][128][32]
#define OFF_P     165376                    // [16][8192][32]
// total = 165376 + 16*8192*32 = 4,359,680 floats ~= 17.4 MB

// ---------------- stage coefficient math (f64) ----------------
__device__ inline void stage_coefs(int i, double fn, double gn, double qn,
                                   double& B0, double& B1, double& B2,
                                   double& A1, double& A2) {
    const double FS = 96000.0;
    double Q    = exp(log(0.5) + qn * (log(16.0) - log(0.5)));
    double gain = -24.0 + gn * 48.0;
    double lo, hi;
    if (i == 0)            { lo = 20.0;   hi = 500.0;   }
    else if (i == 15)      { lo = 5000.0; hi = 20000.0; }
    else if (i == 1 || i == 14) { lo = 50.0; hi = 16000.0; }
    else                   { lo = 100.0;  hi = 15000.0; }
    double fc    = exp(log(lo) + fn * (log(hi) - log(lo)));
    double w0    = 2.0 * DPI * fc / FS;
    double alpha = sin(w0) / (2.0 * Q);
    double c     = cos(w0);
    double b0, b1, b2, a0, a1, a2;
    if (i == 0) {                 // highpass
        b0 = (1.0 + c) * 0.5; b1 = -(1.0 + c); b2 = (1.0 + c) * 0.5;
        a0 = 1.0 + alpha; a1 = -2.0 * c; a2 = 1.0 - alpha;
    } else if (i == 15) {         // lowpass
        b0 = (1.0 - c) * 0.5; b1 = 1.0 - c; b2 = (1.0 - c) * 0.5;
        a0 = 1.0 + alpha; a1 = -2.0 * c; a2 = 1.0 - alpha;
    } else if (i == 1) {          // lowshelf
        double A = pow(10.0, gain / 40.0), sA = sqrt(A);
        b0 = A * ((A + 1.0) - (A - 1.0) * c + 2.0 * sA * alpha);
        b1 = 2.0 * A * ((A - 1.0) - (A + 1.0) * c);
        b2 = A * ((A + 1.0) - (A - 1.0) * c - 2.0 * sA * alpha);
        a0 = (A + 1.0) + (A - 1.0) * c + 2.0 * sA * alpha;
        a1 = -2.0 * ((A - 1.0) + (A + 1.0) * c);
        a2 = (A + 1.0) + (A - 1.0) * c - 2.0 * sA * alpha;
    } else if (i == 14) {         // highshelf
        double A = pow(10.0, gain / 40.0), sA = sqrt(A);
        b0 = A * ((A + 1.0) + (A - 1.0) * c + 2.0 * sA * alpha);
        b1 = -2.0 * A * ((A - 1.0) + (A + 1.0) * c);
        b2 = A * ((A + 1.0) + (A - 1.0) * c - 2.0 * sA * alpha);
        a0 = (A + 1.0) - (A - 1.0) * c + 2.0 * sA * alpha;
        a1 = 2.0 * ((A - 1.0) - (A + 1.0) * c);
        a2 = (A + 1.0) - (A - 1.0) * c - 2.0 * sA * alpha;
    } else {                      // peak
        double A = pow(10.0, gain / 40.0);
        b0 = 1.0 + alpha * A; b1 = -2.0 * c; b2 = 1.0 - alpha * A;
        a0 = 1.0 + alpha / A; a1 = -2.0 * c; a2 = 1.0 - alpha / A;
    }
    B0 = b0 / a0; B1 = b1 / a0; B2 = b2 / a0; A1 = a1 / a0; A2 = a2 / a0;
}

// ---------------- K0: coefs + A^32 + A^2048 per batch ----------------
// thread t owns column c=t&31, rows r0+{0,8,16,24}; per-k column read is 32
// consecutive doubles (2-way bank alias = free), row reads are broadcasts.
__global__ __launch_bounds__(256) void k0_setup(const float* __restrict__ params,
                                                float* __restrict__ coefs,
                                                float* __restrict__ AL,
                                                float* __restrict__ AG) {
    int b = blockIdx.x;
    int t = threadIdx.x;
    __shared__ double cf[NB][5];
    __shared__ double M1[32 * 32];
    __shared__ double M2[32 * 32];

    if (t < NB) {
        double B0, B1, B2, A1, A2;
        stage_coefs(t, (double)params[b * 50 + t * 3 + 0],
                       (double)params[b * 50 + t * 3 + 1],
                       (double)params[b * 50 + t * 3 + 2], B0, B1, B2, A1, A2);
        float f0 = (float)B0, f1 = (float)B1, f2 = (float)B2, f3 = (float)A1, f4 = (float)A2;
        cf[t][0] = (double)f0; cf[t][1] = (double)f1; cf[t][2] = (double)f2;
        cf[t][3] = (double)f3; cf[t][4] = (double)f4;
        float* cp = coefs + b * 96 + t * 5;
        cp[0] = f0; cp[1] = f1; cp[2] = f2; cp[3] = f3; cp[4] = f4;
    }
    if (t == NB) {
        double indb = -60.0 + (double)params[b * 50 + 48] * 60.0;
        coefs[b * 96 + 80] = (float)pow(10.0, indb / 20.0);
    }
    if (t == NB + 1) {
        double outdb = -60.0 + (double)params[b * 50 + 49] * 60.0;
        coefs[b * 96 + 81] = (float)pow(10.0, outdb / 20.0);
    }
    __syncthreads();

    // build A: column t = one cascade step (u=0) applied to unit state e_t
    if (t < 32) {
        double s1[NB], s2[NB];
#pragma unroll
        for (int i = 0; i < NB; i++) {
            s1[i] = (t == 2 * i) ? 1.0 : 0.0;
            s2[i] = (t == 2 * i + 1) ? 1.0 : 0.0;
        }
        double u = 0.0;
#pragma unroll
        for (int i = 0; i < NB; i++) {
            double y  = cf[i][0] * u + s1[i];
            double n1 = cf[i][1] * u - cf[i][3] * y + s2[i];
            double n2 = cf[i][2] * u - cf[i][4] * y;
            s1[i] = n1; s2[i] = n2; u = y;
        }
#pragma unroll
        for (int i = 0; i < NB; i++) {
            M1[(2 * i) * 32 + t]     = s1[i];
            M1[(2 * i + 1) * 32 + t] = s2[i];
        }
    }
    __syncthreads();

    // 11 repeated squarings: after iter sq the matrix is A^(2^(sq+1)).
    // Save A^32 at sq==4, A^2048 at sq==10.
    int c  = t & 31;
    int r0 = t >> 5;
    double* src = M1;
    double* dst = M2;
    for (int sq = 0; sq < 11; sq++) {
        double acc[4] = {0.0, 0.0, 0.0, 0.0};
        for (int k = 0; k < 32; k++) {
            double bv = src[k * 32 + c];
#pragma unroll
            for (int e = 0; e < 4; e++)
                acc[e] += src[(e * 8 + r0) * 32 + k] * bv;
        }
#pragma unroll
        for (int e = 0; e < 4; e++) dst[(e * 8 + r0) * 32 + c] = acc[e];
        __syncthreads();
        { double* tmp = src; src = dst; dst = tmp; }
        if (sq == 4) {
#pragma unroll
            for (int e = 0; e < 4; e++) {
                int idx = (e * 8 + r0) * 32 + c;
                AL[b * 1024 + idx] = (float)src[idx];
            }
        }
        if (sq == 10) {
#pragma unroll
            for (int e = 0; e < 4; e++) {
                int idx = (e * 8 + r0) * 32 + c;
                AG[b * 1024 + idx] = (float)src[idx];
            }
        }
        __syncthreads();
    }
}

// Half-split matvec prefix: lane=(row=lane&31, half=lane>>5); each lane owns
// 16 row coefficients in registers, 16 bpermute+FMA, one shfl_xor(32) merge.

// ---------------- K1: zero-init chunk states + group-final states ----------------
__global__ __launch_bounds__(64, 2) void k1_pass1(const float* __restrict__ audio,
                                                  const float* __restrict__ coefs,
                                                  const float* __restrict__ AL,
                                                  float* __restrict__ P,
                                                  float* __restrict__ Qend) {
    int blk   = blockIdx.x;          // 0..2047
    int batch = blk >> 7;
    int grp   = blk & 127;
    int lane  = threadIdx.x;
    int chunk = grp * GRP + lane;    // 0..8191

    // all chunk loads up front (ILP); 8 float4 = 32 VGPRs
    const float4* xp = (const float4*)(audio + (size_t)batch * T_LEN + (size_t)chunk * L);
    float4 xbuf[L / 4];
#pragma unroll
    for (int tt = 0; tt < L / 4; tt++) xbuf[tt] = xp[tt];

    const float* cf = coefs + batch * 96;
    float c0[NB], c1[NB], c2[NB], c3[NB], c4[NB];
#pragma unroll
    for (int i = 0; i < NB; i++) {
        c0[i] = cf[i * 5 + 0]; c1[i] = cf[i * 5 + 1]; c2[i] = cf[i * 5 + 2];
        c3[i] = cf[i * 5 + 3]; c4[i] = cf[i * 5 + 4];
    }
    float ing = cf[80];

    float s1[NB], s2[NB];
#pragma unroll
    for (int i = 0; i < NB; i++) { s1[i] = 0.f; s2[i] = 0.f; }

#pragma unroll
    for (int tt = 0; tt < L / 4; tt++) {
        float xs[4] = {xbuf[tt].x, xbuf[tt].y, xbuf[tt].z, xbuf[tt].w};
#pragma unroll
        for (int j = 0; j < 4; j++) {
            float u = ing * xs[j];
#pragma unroll
            for (int i = 0; i < NB; i++) {
                float y  = fmaf(c0[i], u, s1[i]);
                float n1 = fmaf(c1[i], u, s2[i]); n1 = fmaf(-c3[i], y, n1);
                float n2 = c2[i] * u;             n2 = fmaf(-c4[i], y, n2);
                s1[i] = n1; s2[i] = n2; u = y;
            }
        }
    }

    // write chunk-final state, also stage into LDS for the group prefix
    __shared__ float plds[GRP][33];
    float* pp = P + ((size_t)(batch * NCHUNK + chunk)) * 32;
#pragma unroll
    for (int i = 0; i < NB; i++) {
        float2 v; v.x = s1[i]; v.y = s2[i];
        *(float2*)(pp + 2 * i) = v;
        plds[lane][2 * i]     = s1[i];
        plds[lane][2 * i + 1] = s2[i];
    }
    __syncthreads();

    // in-wave sequential group prefix: q <- A^32 q + p(k), q0 = 0 (half-split)
    int row  = lane & 31;
    int half = lane >> 5;
    const float* alr = AL + batch * 1024 + row * 32 + half * 16;
    float ar[16];
#pragma unroll
    for (int j = 0; j < 16; j++) ar[j] = alr[j];
    float q = 0.f;
    for (int k = 0; k < GRP; k++) {
        float acc = (half == 0) ? plds[k][row] : 0.f;
#pragma unroll
        for (int j = 0; j < 16; j++)
            acc = fmaf(ar[j], __shfl(q, half * 16 + j, 64), acc);
        acc += __shfl_xor(acc, 32, 64);
        q = acc;
    }
    if (lane < 32) Qend[(batch * NG + grp) * 32 + row] = q;
}

// ---------------- K2: group-level sequential combine per batch ----------------
__global__ __launch_bounds__(64, 1) void k2_combine(const float* __restrict__ AG,
                                                    const float* __restrict__ Qend,
                                                    float* __restrict__ Sarr) {
    int batch = blockIdx.x;
    int lane  = threadIdx.x;
    int row   = lane & 31;
    int half  = lane >> 5;

    __shared__ float qe[NG][32];
    __shared__ float ss[NG][32];

    // cooperative coalesced load of Qend[batch] (16 KB) into LDS
    const float4* qsrc = (const float4*)(Qend + (size_t)batch * NG * 32);
    float4* qdst = (float4*)&qe[0][0];
    for (int i = lane; i < NG * 32 / 4; i += 64) qdst[i] = qsrc[i];

    const float* agr = AG + batch * 1024 + row * 32 + half * 16;
    float ar[16];
#pragma unroll
    for (int j = 0; j < 16; j++) ar[j] = agr[j];
    __syncthreads();

    float S = 0.f;
    for (int g = 0; g < NG; g++) {
        if (half == 0) ss[g][row] = S;        // state at start of group g
        float acc = (half == 0) ? qe[g][row] : 0.f;
#pragma unroll
        for (int j = 0; j < 16; j++)
            acc = fmaf(ar[j], __shfl(S, half * 16 + j, 64), acc);
        acc += __shfl_xor(acc, 32, 64);
        S = acc;
    }
    __syncthreads();

    // coalesced dump of start states
    const float4* s4 = (const float4*)&ss[0][0];
    float4* sd = (float4*)(Sarr + (size_t)batch * NG * 32);
    for (int i = lane; i < NG * 32 / 4; i += 64) sd[i] = s4[i];
}

// ---------------- K3: corrected-init re-run, write output ----------------
__global__ __launch_bounds__(64, 2) void k3_pass2(const float* __restrict__ audio,
                                                  const float* __restrict__ coefs,
                                                  const float* __restrict__ AL,
                                                  const float* __restrict__ P,
                                                  const float* __restrict__ Sarr,
                                                  float* __restrict__ out) {
    int blk   = blockIdx.x;
    int batch = blk >> 7;
    int grp   = blk & 127;
    int lane  = threadIdx.x;
    int chunk = grp * GRP + lane;

    // audio loads first (longest latency, used last)
    const float4* xp = (const float4*)(audio + (size_t)batch * T_LEN + (size_t)chunk * L);
    float4 xbuf[L / 4];
#pragma unroll
    for (int tt = 0; tt < L / 4; tt++) xbuf[tt] = xp[tt];

    __shared__ float plds[GRP][33];

    const float4* pp4 = (const float4*)(P + ((size_t)(batch * NCHUNK + chunk)) * 32);
#pragma unroll
    for (int r4 = 0; r4 < 8; r4++) {
        float4 v = pp4[r4];
        plds[lane][4 * r4 + 0] = v.x;
        plds[lane][4 * r4 + 1] = v.y;
        plds[lane][4 * r4 + 2] = v.z;
        plds[lane][4 * r4 + 3] = v.w;
    }
    __syncthreads();

    // group prefix seeded with true group start state (half-split).
    // In-place: read p(k), overwrite plds[k][row] with chunk-k start state
    // (same lane reads then writes -> no hazard; saves the second LDS buffer).
    {
        int row  = lane & 31;
        int half = lane >> 5;
        const float* alr = AL + batch * 1024 + row * 32 + half * 16;
        float ar[16];
#pragma unroll
        for (int j = 0; j < 16; j++) ar[j] = alr[j];
        float q = Sarr[(batch * NG + grp) * 32 + row];   // replicated in both halves
        for (int k = 0; k < GRP; k++) {
            float p = (half == 0) ? plds[k][row] : 0.f;
            if (half == 0) plds[k][row] = q;             // s_start of chunk
            float acc = p;
#pragma unroll
            for (int j = 0; j < 16; j++)
                acc = fmaf(ar[j], __shfl(q, half * 16 + j, 64), acc);
            acc += __shfl_xor(acc, 32, 64);
            q = acc;
        }
    }
    __syncthreads();

    const float* cf = coefs + batch * 96;
    float c0[NB], c1[NB], c2[NB], c3[NB], c4[NB];
#pragma unroll
    for (int i = 0; i < NB; i++) {
        c0[i] = cf[i * 5 + 0]; c1[i] = cf[i * 5 + 1]; c2[i] = cf[i * 5 + 2];
        c3[i] = cf[i * 5 + 3]; c4[i] = cf[i * 5 + 4];
    }
    float ing  = cf[80];
    float outg = cf[81];

    float s1[NB], s2[NB];
#pragma unroll
    for (int i = 0; i < NB; i++) {
        s1[i] = plds[lane][2 * i];
        s2[i] = plds[lane][2 * i + 1];
    }

    float4* yp = (float4*)(out + (size_t)batch * T_LEN + (size_t)chunk * L);
#pragma unroll
    for (int tt = 0; tt < L / 4; tt++) {
        float xs[4] = {xbuf[tt].x, xbuf[tt].y, xbuf[tt].z, xbuf[tt].w};
        float ys[4];
#pragma unroll
        for (int j = 0; j < 4; j++) {
            float u = ing * xs[j];
#pragma unroll
            for (int i = 0; i < NB; i++) {
                float y  = fmaf(c0[i], u, s1[i]);
                float n1 = fmaf(c1[i], u, s2[i]); n1 = fmaf(-c3[i], y, n1);
                float n2 = c2[i] * u;             n2 = fmaf(-c4[i], y, n2);
                s1[i] = n1; s2[i] = n2; u = y;
            }
            ys[j] = outg * u;
        }
        float4 yv; yv.x = ys[0]; yv.y = ys[1]; yv.z = ys[2]; yv.w = ys[3];
        yp[tt] = yv;
    }
}

// ---------------- launcher ----------------
extern "C" void kernel_launch(void* const* d_in, const int* in_sizes, int n_in,
                              void* d_out, int out_size, void* d_ws, size_t ws_size,
                              hipStream_t stream) {
    const float* audio  = (const float*)d_in[0];
    const float* params = (const float*)d_in[1];
    float* out = (float*)d_out;
    float* ws  = (float*)d_ws;

    float* coefs = ws + OFF_COEF;
    float* AL    = ws + OFF_AL;
    float* AG    = ws + OFF_AG;
    float* Qend  = ws + OFF_QEND;
    float* Sarr  = ws + OFF_SARR;
    float* P     = ws + OFF_P;

    k0_setup<<<BATCH, 256, 0, stream>>>(params, coefs, AL, AG);
    k1_pass1<<<BATCH * NG, 64, 0, stream>>>(audio, coefs, AL, P, Qend);
    k2_combine<<<BATCH, 64, 0, stream>>>(AG, Qend, Sarr);
    k3_pass2<<<BATCH * NG, 64, 0, stream>>>(audio, coefs, AL, P, Sarr, out);
}

// Round 5
// 159.470 us; speedup vs baseline: 1.1717x; 1.1717x over previous
//
#include <hip/hip_runtime.h>
#include <math.h>

// ---------------- problem constants ----------------
#define BATCH   16
#define T_LEN   262144
#define NB      16          // biquad stages
#define L       64          // samples per chunk
#define GRP     64          // chunks per group (== wave width)
#define SUB     16          // chunks per sub-group (prefix chain length)
#define CHAINS  4           // sub-groups per wave (GRP/SUB)
#define NSUB    256         // sub-groups per batch (NCHUNK/SUB)
#define NSUP    16          // super-groups per batch (NSUB/16)
#define NG      64          // groups (waves) per batch
#define NCHUNK  4096        // chunks per batch

#define DPI 3.14159265358979323846264338327950288

// ---------------- ws layout (in floats) ----------------
#define OFF_COEF   0            // [16][96]
#define OFF_A64    1536         // [16][32][32]  A^64
#define OFF_A1K    17920        // [16][32][32]  A^1024
#define OFF_A16K   34304        // [16][32][32]  A^16384
#define OFF_QEND   50688        // [16][256][32] zero-init sub-group totals
#define OFF_QSUP   181760       // [16][16][32]  zero-init super totals
#define OFF_SSUP   189952       // [16][16][32]  super start states
#define OFF_SARR   198144       // [16][256][32] sub-group start states
#define OFF_P      329216       // [16][4096][32] zero-init chunk-final states
// total = 329216 + 16*4096*32 = 2,426,368 floats ~= 9.7 MB

// ---------------- stage coefficient math (f64) ----------------
__device__ inline void stage_coefs(int i, double fn, double gn, double qn,
                                   double& B0, double& B1, double& B2,
                                   double& A1, double& A2) {
    const double FS = 96000.0;
    double Q    = exp(log(0.5) + qn * (log(16.0) - log(0.5)));
    double gain = -24.0 + gn * 48.0;
    double lo, hi;
    if (i == 0)            { lo = 20.0;   hi = 500.0;   }
    else if (i == 15)      { lo = 5000.0; hi = 20000.0; }
    else if (i == 1 || i == 14) { lo = 50.0; hi = 16000.0; }
    else                   { lo = 100.0;  hi = 15000.0; }
    double fc    = exp(log(lo) + fn * (log(hi) - log(lo)));
    double w0    = 2.0 * DPI * fc / FS;
    double alpha = sin(w0) / (2.0 * Q);
    double c     = cos(w0);
    double b0, b1, b2, a0, a1, a2;
    if (i == 0) {                 // highpass
        b0 = (1.0 + c) * 0.5; b1 = -(1.0 + c); b2 = (1.0 + c) * 0.5;
        a0 = 1.0 + alpha; a1 = -2.0 * c; a2 = 1.0 - alpha;
    } else if (i == 15) {         // lowpass
        b0 = (1.0 - c) * 0.5; b1 = 1.0 - c; b2 = (1.0 - c) * 0.5;
        a0 = 1.0 + alpha; a1 = -2.0 * c; a2 = 1.0 - alpha;
    } else if (i == 1) {          // lowshelf
        double A = pow(10.0, gain / 40.0), sA = sqrt(A);
        b0 = A * ((A + 1.0) - (A - 1.0) * c + 2.0 * sA * alpha);
        b1 = 2.0 * A * ((A - 1.0) - (A + 1.0) * c);
        b2 = A * ((A + 1.0) - (A - 1.0) * c - 2.0 * sA * alpha);
        a0 = (A + 1.0) + (A - 1.0) * c + 2.0 * sA * alpha;
        a1 = -2.0 * ((A - 1.0) + (A + 1.0) * c);
        a2 = (A + 1.0) + (A - 1.0) * c - 2.0 * sA * alpha;
    } else if (i == 14) {         // highshelf
        double A = pow(10.0, gain / 40.0), sA = sqrt(A);
        b0 = A * ((A + 1.0) + (A - 1.0) * c + 2.0 * sA * alpha);
        b1 = -2.0 * A * ((A - 1.0) + (A + 1.0) * c);
        b2 = A * ((A + 1.0) + (A - 1.0) * c - 2.0 * sA * alpha);
        a0 = (A + 1.0) - (A - 1.0) * c + 2.0 * sA * alpha;
        a1 = 2.0 * ((A - 1.0) - (A + 1.0) * c);
        a2 = (A + 1.0) - (A - 1.0) * c - 2.0 * sA * alpha;
    } else {                      // peak
        double A = pow(10.0, gain / 40.0);
        b0 = 1.0 + alpha * A; b1 = -2.0 * c; b2 = 1.0 - alpha * A;
        a0 = 1.0 + alpha / A; a1 = -2.0 * c; a2 = 1.0 - alpha / A;
    }
    B0 = b0 / a0; B1 = b1 / a0; B2 = b2 / a0; A1 = a1 / a0; A2 = a2 / a0;
}

// ---------------- K0: coefs + A^64 / A^1024 / A^16384 per batch ----------------
__global__ __launch_bounds__(256) void k0_setup(const float* __restrict__ params,
                                                float* __restrict__ coefs,
                                                float* __restrict__ A64,
                                                float* __restrict__ A1K,
                                                float* __restrict__ A16K) {
    int b = blockIdx.x;
    int t = threadIdx.x;
    __shared__ double cf[NB][5];
    __shared__ double M1[32 * 32];
    __shared__ double M2[32 * 32];

    if (t < NB) {
        double B0, B1, B2, A1, A2;
        stage_coefs(t, (double)params[b * 50 + t * 3 + 0],
                       (double)params[b * 50 + t * 3 + 1],
                       (double)params[b * 50 + t * 3 + 2], B0, B1, B2, A1, A2);
        float f0 = (float)B0, f1 = (float)B1, f2 = (float)B2, f3 = (float)A1, f4 = (float)A2;
        cf[t][0] = (double)f0; cf[t][1] = (double)f1; cf[t][2] = (double)f2;
        cf[t][3] = (double)f3; cf[t][4] = (double)f4;
        float* cp = coefs + b * 96 + t * 5;
        cp[0] = f0; cp[1] = f1; cp[2] = f2; cp[3] = f3; cp[4] = f4;
    }
    if (t == NB) {
        double indb = -60.0 + (double)params[b * 50 + 48] * 60.0;
        coefs[b * 96 + 80] = (float)pow(10.0, indb / 20.0);
    }
    if (t == NB + 1) {
        double outdb = -60.0 + (double)params[b * 50 + 49] * 60.0;
        coefs[b * 96 + 81] = (float)pow(10.0, outdb / 20.0);
    }
    __syncthreads();

    // build A: column t = one cascade step (u=0) applied to unit state e_t
    if (t < 32) {
        double s1[NB], s2[NB];
#pragma unroll
        for (int i = 0; i < NB; i++) {
            s1[i] = (t == 2 * i) ? 1.0 : 0.0;
            s2[i] = (t == 2 * i + 1) ? 1.0 : 0.0;
        }
        double u = 0.0;
#pragma unroll
        for (int i = 0; i < NB; i++) {
            double y  = cf[i][0] * u + s1[i];
            double n1 = cf[i][1] * u - cf[i][3] * y + s2[i];
            double n2 = cf[i][2] * u - cf[i][4] * y;
            s1[i] = n1; s2[i] = n2; u = y;
        }
#pragma unroll
        for (int i = 0; i < NB; i++) {
            M1[(2 * i) * 32 + t]     = s1[i];
            M1[(2 * i + 1) * 32 + t] = s2[i];
        }
    }
    __syncthreads();

    // 14 repeated squarings; after iter sq: A^(2^(sq+1)).
    // Save A^64 (sq=5), A^1024 (sq=9), A^16384 (sq=13).
    // thread t: column c=t&31, rows r0+{0,8,16,24}; column read = 32
    // consecutive doubles (2-way bank alias = free), row reads broadcast.
    int c  = t & 31;
    int r0 = t >> 5;
    double* src = M1;
    double* dst = M2;
    for (int sq = 0; sq < 14; sq++) {
        double acc[4] = {0.0, 0.0, 0.0, 0.0};
        for (int k = 0; k < 32; k++) {
            double bv = src[k * 32 + c];
#pragma unroll
            for (int e = 0; e < 4; e++)
                acc[e] += src[(e * 8 + r0) * 32 + k] * bv;
        }
#pragma unroll
        for (int e = 0; e < 4; e++) dst[(e * 8 + r0) * 32 + c] = acc[e];
        __syncthreads();
        { double* tmp = src; src = dst; dst = tmp; }
        float* out_m = (sq == 5) ? A64 : (sq == 9) ? A1K : (sq == 13) ? A16K : nullptr;
        if (out_m) {
#pragma unroll
            for (int e = 0; e < 4; e++) {
                int idx = (e * 8 + r0) * 32 + c;
                out_m[b * 1024 + idx] = (float)src[idx];
            }
        }
        __syncthreads();
    }
}

// ---------------- K1: zero-init chunk states + sub-group totals ----------------
__global__ __launch_bounds__(64, 1) void k1_pass1(const float* __restrict__ audio,
                                                  const float* __restrict__ coefs,
                                                  const float* __restrict__ A64,
                                                  float* __restrict__ P,
                                                  float* __restrict__ Qend) {
    int blk   = blockIdx.x;          // 0..1023
    int batch = blk >> 6;
    int grp   = blk & 63;
    int lane  = threadIdx.x;
    int chunk = grp * GRP + lane;

    const float* cf = coefs + batch * 96;
    float c0[NB], c1[NB], c2[NB], c3[NB], c4[NB];
#pragma unroll
    for (int i = 0; i < NB; i++) {
        c0[i] = cf[i * 5 + 0]; c1[i] = cf[i * 5 + 1]; c2[i] = cf[i * 5 + 2];
        c3[i] = cf[i * 5 + 3]; c4[i] = cf[i * 5 + 4];
    }
    float ing = cf[80];

    float s1[NB], s2[NB];
#pragma unroll
    for (int i = 0; i < NB; i++) { s1[i] = 0.f; s2[i] = 0.f; }

    // rolled cascade loop (body ~2.6 KB, icache-resident), 2-deep prefetch
    const float4* xp = (const float4*)(audio + (size_t)batch * T_LEN + (size_t)chunk * L);
    float4 cur = xp[0];
    float4 nxt = xp[1];
#pragma unroll 1
    for (int tt = 0; tt < 16; tt++) {
        float4 fut = xp[(tt < 14) ? (tt + 2) : 15];
        float xs[4] = {cur.x, cur.y, cur.z, cur.w};
#pragma unroll
        for (int j = 0; j < 4; j++) {
            float u = ing * xs[j];
#pragma unroll
            for (int i = 0; i < NB; i++) {
                float y  = fmaf(c0[i], u, s1[i]);
                float n1 = fmaf(c1[i], u, s2[i]); n1 = fmaf(-c3[i], y, n1);
                float n2 = c2[i] * u;             n2 = fmaf(-c4[i], y, n2);
                s1[i] = n1; s2[i] = n2; u = y;
            }
        }
        cur = nxt; nxt = fut;
    }

    // write chunk-final state, stage into LDS for the chains
    __shared__ float plds[GRP][33];
    float* pp = P + ((size_t)(batch * NCHUNK + chunk)) * 32;
#pragma unroll
    for (int i = 0; i < NB; i++) {
        float2 v; v.x = s1[i]; v.y = s2[i];
        *(float2*)(pp + 2 * i) = v;
        plds[lane][2 * i]     = s1[i];
        plds[lane][2 * i + 1] = s2[i];
    }
    __syncthreads();

    // 4 independent 16-step chains (half-split matvec): chain c covers
    // chunks c*16..c*16+15; serial depth 16 with 4-way ILP.
    int row  = lane & 31;
    int half = lane >> 5;
    const float* alr = A64 + batch * 1024 + row * 32 + half * 16;
    float ar[16];
#pragma unroll
    for (int j = 0; j < 16; j++) ar[j] = alr[j];
    float q0 = 0.f, q1 = 0.f, q2 = 0.f, q3 = 0.f;
#pragma unroll 1
    for (int j = 0; j < SUB; j++) {
        float a0 = (half == 0) ? plds[0 * SUB + j][row] : 0.f;
        float a1 = (half == 0) ? plds[1 * SUB + j][row] : 0.f;
        float a2 = (half == 0) ? plds[2 * SUB + j][row] : 0.f;
        float a3 = (half == 0) ? plds[3 * SUB + j][row] : 0.f;
#pragma unroll
        for (int t = 0; t < 16; t++) {
            float w = ar[t];
            int src = half * 16 + t;
            a0 = fmaf(w, __shfl(q0, src, 64), a0);
            a1 = fmaf(w, __shfl(q1, src, 64), a1);
            a2 = fmaf(w, __shfl(q2, src, 64), a2);
            a3 = fmaf(w, __shfl(q3, src, 64), a3);
        }
        a0 += __shfl_xor(a0, 32, 64);
        a1 += __shfl_xor(a1, 32, 64);
        a2 += __shfl_xor(a2, 32, 64);
        a3 += __shfl_xor(a3, 32, 64);
        q0 = a0; q1 = a1; q2 = a2; q3 = a3;
    }
    if (lane < 32) {
        float* qe = Qend + ((size_t)(batch * NSUB + grp * CHAINS)) * 32 + row;
        qe[0 * 32] = q0; qe[1 * 32] = q1; qe[2 * 32] = q2; qe[3 * 32] = q3;
    }
}

// ---------------- K2a: sub-group totals -> super totals ----------------
__global__ __launch_bounds__(64, 1) void k2a(const float* __restrict__ A1K,
                                             const float* __restrict__ Qend,
                                             float* __restrict__ Qsup) {
    int batch = blockIdx.x >> 4;
    int sup   = blockIdx.x & 15;
    int lane  = threadIdx.x;
    int row   = lane & 31;
    int half  = lane >> 5;

    float pv[16];
#pragma unroll
    for (int j = 0; j < 16; j++)
        pv[j] = (half == 0) ? Qend[((size_t)(batch * NSUB + sup * 16 + j)) * 32 + row] : 0.f;

    const float* agr = A1K + batch * 1024 + row * 32 + half * 16;
    float ar[16];
#pragma unroll
    for (int j = 0; j < 16; j++) ar[j] = agr[j];

    float q = 0.f;
#pragma unroll 1
    for (int j = 0; j < 16; j++) {
        float acc = pv[j];
#pragma unroll
        for (int t = 0; t < 16; t++)
            acc = fmaf(ar[t], __shfl(q, half * 16 + t, 64), acc);
        acc += __shfl_xor(acc, 32, 64);
        q = acc;
    }
    if (lane < 32) Qsup[((size_t)(batch * NSUP + sup)) * 32 + row] = q;
}

// ---------------- K2b: scan supers -> super start states ----------------
__global__ __launch_bounds__(64, 1) void k2b(const float* __restrict__ A16K,
                                             const float* __restrict__ Qsup,
                                             float* __restrict__ Ssup) {
    int batch = blockIdx.x;
    int lane  = threadIdx.x;
    int row   = lane & 31;
    int half  = lane >> 5;

    float pv[16];
#pragma unroll
    for (int j = 0; j < 16; j++)
        pv[j] = (half == 0) ? Qsup[((size_t)(batch * NSUP + j)) * 32 + row] : 0.f;

    const float* agr = A16K + batch * 1024 + row * 32 + half * 16;
    float ar[16];
#pragma unroll
    for (int j = 0; j < 16; j++) ar[j] = agr[j];

    float S = 0.f;
#pragma unroll 1
    for (int s = 0; s < 16; s++) {
        if (lane < 32) Ssup[((size_t)(batch * NSUP + s)) * 32 + row] = S;
        float acc = pv[s];
#pragma unroll
        for (int t = 0; t < 16; t++)
            acc = fmaf(ar[t], __shfl(S, half * 16 + t, 64), acc);
        acc += __shfl_xor(acc, 32, 64);
        S = acc;
    }
}

// ---------------- K2c: seeded re-run -> all sub-group start states ----------------
__global__ __launch_bounds__(64, 1) void k2c(const float* __restrict__ A1K,
                                             const float* __restrict__ Qend,
                                             const float* __restrict__ Ssup,
                                             float* __restrict__ Sarr) {
    int batch = blockIdx.x >> 4;
    int sup   = blockIdx.x & 15;
    int lane  = threadIdx.x;
    int row   = lane & 31;
    int half  = lane >> 5;

    float pv[16];
#pragma unroll
    for (int j = 0; j < 16; j++)
        pv[j] = (half == 0) ? Qend[((size_t)(batch * NSUB + sup * 16 + j)) * 32 + row] : 0.f;

    const float* agr = A1K + batch * 1024 + row * 32 + half * 16;
    float ar[16];
#pragma unroll
    for (int j = 0; j < 16; j++) ar[j] = agr[j];

    float q = Ssup[((size_t)(batch * NSUP + sup)) * 32 + row];  // same in both halves
#pragma unroll 1
    for (int j = 0; j < 16; j++) {
        if (lane < 32) Sarr[((size_t)(batch * NSUB + sup * 16 + j)) * 32 + row] = q;
        float acc = pv[j];
#pragma unroll
        for (int t = 0; t < 16; t++)
            acc = fmaf(ar[t], __shfl(q, half * 16 + t, 64), acc);
        acc += __shfl_xor(acc, 32, 64);
        q = acc;
    }
}

// ---------------- K3: corrected-init re-run, write output ----------------
__global__ __launch_bounds__(64, 1) void k3_pass2(const float* __restrict__ audio,
                                                  const float* __restrict__ coefs,
                                                  const float* __restrict__ A64,
                                                  const float* __restrict__ P,
                                                  const float* __restrict__ Sarr,
                                                  float* __restrict__ out) {
    int blk   = blockIdx.x;
    int batch = blk >> 6;
    int grp   = blk & 63;
    int lane  = threadIdx.x;
    int chunk = grp * GRP + lane;

    __shared__ float plds[GRP][33];

    const float4* pp4 = (const float4*)(P + ((size_t)(batch * NCHUNK + chunk)) * 32);
#pragma unroll
    for (int r4 = 0; r4 < 8; r4++) {
        float4 v = pp4[r4];
        plds[lane][4 * r4 + 0] = v.x;
        plds[lane][4 * r4 + 1] = v.y;
        plds[lane][4 * r4 + 2] = v.z;
        plds[lane][4 * r4 + 3] = v.w;
    }
    __syncthreads();

    // 4 seeded chains; overwrite plds[k][row] in place with chunk-k start state
    {
        int row  = lane & 31;
        int half = lane >> 5;
        const float* alr = A64 + batch * 1024 + row * 32 + half * 16;
        float ar[16];
#pragma unroll
        for (int j = 0; j < 16; j++) ar[j] = alr[j];
        const float* sp = Sarr + ((size_t)(batch * NSUB + grp * CHAINS)) * 32 + row;
        float q0 = sp[0 * 32], q1 = sp[1 * 32], q2 = sp[2 * 32], q3 = sp[3 * 32];
#pragma unroll 1
        for (int j = 0; j < SUB; j++) {
            float a0 = (half == 0) ? plds[0 * SUB + j][row] : 0.f;
            float a1 = (half == 0) ? plds[1 * SUB + j][row] : 0.f;
            float a2 = (half == 0) ? plds[2 * SUB + j][row] : 0.f;
            float a3 = (half == 0) ? plds[3 * SUB + j][row] : 0.f;
            if (half == 0) {
                plds[0 * SUB + j][row] = q0;
                plds[1 * SUB + j][row] = q1;
                plds[2 * SUB + j][row] = q2;
                plds[3 * SUB + j][row] = q3;
            }
#pragma unroll
            for (int t = 0; t < 16; t++) {
                float w = ar[t];
                int src = half * 16 + t;
                a0 = fmaf(w, __shfl(q0, src, 64), a0);
                a1 = fmaf(w, __shfl(q1, src, 64), a1);
                a2 = fmaf(w, __shfl(q2, src, 64), a2);
                a3 = fmaf(w, __shfl(q3, src, 64), a3);
            }
            a0 += __shfl_xor(a0, 32, 64);
            a1 += __shfl_xor(a1, 32, 64);
            a2 += __shfl_xor(a2, 32, 64);
            a3 += __shfl_xor(a3, 32, 64);
            q0 = a0; q1 = a1; q2 = a2; q3 = a3;
        }
    }
    __syncthreads();

    const float* cf = coefs + batch * 96;
    float c0[NB], c1[NB], c2[NB], c3[NB], c4[NB];
#pragma unroll
    for (int i = 0; i < NB; i++) {
        c0[i] = cf[i * 5 + 0]; c1[i] = cf[i * 5 + 1]; c2[i] = cf[i * 5 + 2];
        c3[i] = cf[i * 5 + 3]; c4[i] = cf[i * 5 + 4];
    }
    float ing  = cf[80];
    float outg = cf[81];

    float s1[NB], s2[NB];
#pragma unroll
    for (int i = 0; i < NB; i++) {
        s1[i] = plds[lane][2 * i];
        s2[i] = plds[lane][2 * i + 1];
    }

    const float4* xp = (const float4*)(audio + (size_t)batch * T_LEN + (size_t)chunk * L);
    float4* yp = (float4*)(out + (size_t)batch * T_LEN + (size_t)chunk * L);
    float4 cur = xp[0];
    float4 nxt = xp[1];
#pragma unroll 1
    for (int tt = 0; tt < 16; tt++) {
        float4 fut = xp[(tt < 14) ? (tt + 2) : 15];
        float xs[4] = {cur.x, cur.y, cur.z, cur.w};
        float ys[4];
#pragma unroll
        for (int j = 0; j < 4; j++) {
            float u = ing * xs[j];
#pragma unroll
            for (int i = 0; i < NB; i++) {
                float y  = fmaf(c0[i], u, s1[i]);
                float n1 = fmaf(c1[i], u, s2[i]); n1 = fmaf(-c3[i], y, n1);
                float n2 = c2[i] * u;             n2 = fmaf(-c4[i], y, n2);
                s1[i] = n1; s2[i] = n2; u = y;
            }
            ys[j] = outg * u;
        }
        float4 yv; yv.x = ys[0]; yv.y = ys[1]; yv.z = ys[2]; yv.w = ys[3];
        yp[tt] = yv;
        cur = nxt; nxt = fut;
    }
}

// ---------------- launcher ----------------
extern "C" void kernel_launch(void* const* d_in, const int* in_sizes, int n_in,
                              void* d_out, int out_size, void* d_ws, size_t ws_size,
                              hipStream_t stream) {
    const float* audio  = (const float*)d_in[0];
    const float* params = (const float*)d_in[1];
    float* out = (float*)d_out;
    float* ws  = (float*)d_ws;

    float* coefs = ws + OFF_COEF;
    float* A64   = ws + OFF_A64;
    float* A1K   = ws + OFF_A1K;
    float* A16K  = ws + OFF_A16K;
    float* Qend  = ws + OFF_QEND;
    float* Qsup  = ws + OFF_QSUP;
    float* Ssup  = ws + OFF_SSUP;
    float* Sarr  = ws + OFF_SARR;
    float* P     = ws + OFF_P;

    k0_setup<<<BATCH, 256, 0, stream>>>(params, coefs, A64, A1K, A16K);
    k1_pass1<<<BATCH * NG, 64, 0, stream>>>(audio, coefs, A64, P, Qend);
    k2a<<<BATCH * NSUP, 64, 0, stream>>>(A1K, Qend, Qsup);
    k2b<<<BATCH, 64, 0, stream>>>(A16K, Qsup, Ssup);
    k2c<<<BATCH * NSUP, 64, 0, stream>>>(A1K, Qend, Ssup, Sarr);
    k3_pass2<<<BATCH * NG, 64, 0, stream>>>(audio, coefs, A64, P, Sarr, out);
}